// Round 11
// baseline (154.393 us; speedup 1.0000x reference)
//
#include <hip/hip_runtime.h>
#include <hip/hip_bf16.h>
#include <math.h>

#define BB 2
#define SS 4096
#define DD 512
#define HH 8
#define HD 64
#define MSD (BB*SS*DD)          // 4194304 elements per matrix
#define WSZ (DD*DD)             // 262144 elements per weight

// ws layout (ushort elements):
//   Qb @ 0      [bh][s][hd]  (pre-scaled by log2e/sqrt(512))
//   Kb @ MSD    [bh][s][hd]
//   Vt @ 2*MSD  [bh][hd][s]
//   xb @ 4*MSD  [m][k]            (dead after qkv)
//   Wb @ 5*MSD  3 x [n][k]        (dead after qkv)
//   Opart @ 3*MSD (as f32): 512 x 128 x 64 f32 = 16.78MB, overlays [3*MSD,5*MSD)
//   Lpart @ 5*MSD (as f32): 512 x 128 f32, overlays Wb
#define XOFF (4*(size_t)MSD)
#define WOFF (5*(size_t)MSD)
#define POFF (3*(size_t)MSD)

typedef __attribute__((ext_vector_type(8))) short bf16x8;
typedef __attribute__((ext_vector_type(4))) float f32x4;

__device__ __forceinline__ unsigned short f2bf(float f) {
    unsigned int u = __float_as_uint(f);
    u += 0x7fff + ((u >> 16) & 1);
    return (unsigned short)(u >> 16);
}
__device__ __forceinline__ unsigned int pk2bf(float a, float b) {
    __hip_bfloat162 h = __float22bfloat162_rn(make_float2(a, b));
    union { __hip_bfloat162 h2; unsigned int u; } cv; cv.h2 = h;
    return cv.u;   // low 16 = a, high 16 = b
}

#define GLD16(gsrc, ldst) \
    __builtin_amdgcn_global_load_lds((const __attribute__((address_space(1))) unsigned int*)(gsrc), \
                                     (__attribute__((address_space(3))) unsigned int*)(ldst), 16, 0, 0)

// ---------------------------------------------------------------------------
// Balanced schedule: per bh, 48 chunks packed into 16 triples summing to 66.
// Block bx = k*256 + ti*16 + bh: {j, j+256, j+512} share a CU.
// ---------------------------------------------------------------------------
#define CH(qb,t0,t1) ((unsigned)(qb) | ((unsigned)(t0)<<8) | ((unsigned)(t1)<<16))
__device__ __constant__ unsigned int SCHED[48] = {
  CH(31,0,32),  CH(31,32,64), CH(0,0,2),     // 32+32+2
  CH(15,0,32),  CH(29,0,30),  CH(1,0,4),     // 32+30+4
  CH(29,30,60), CH(14,0,30),  CH(2,0,6),     // 30+30+6
  CH(28,0,29),  CH(28,29,58), CH(3,0,8),     // 29+29+8
  CH(27,0,28),  CH(13,0,28),  CH(4,0,10),    // 28+28+10
  CH(26,0,27),  CH(26,27,54), CH(5,0,12),    // 27+27+12
  CH(25,0,26),  CH(12,0,26),  CH(6,0,14),    // 26+26+14
  CH(24,0,25),  CH(24,25,50), CH(7,0,16),    // 25+25+16
  CH(30,0,31),  CH(17,0,18),  CH(16,0,17),   // 31+18+17
  CH(30,31,62), CH(17,18,36), CH(16,17,34),  // 31+18+17
  CH(27,28,56), CH(19,0,20),  CH(8,0,18),    // 28+20+18
  CH(25,26,52), CH(20,0,21),  CH(18,0,19),   // 26+21+19
  CH(23,0,24),  CH(22,0,23),  CH(18,19,38),  // 24+23+19
  CH(23,24,48), CH(21,0,22),  CH(19,20,40),  // 24+22+20
  CH(11,0,24),  CH(21,22,44), CH(9,0,20),    // 24+22+20
  CH(22,23,46), CH(10,0,22),  CH(20,21,42),  // 23+22+21
};

// ---------------------------------------------------------------------------
// fp32 -> bf16 convert: x (MSD els) and Wq|Wk|Wv (3*WSZ els). 8 els/thread.
// ---------------------------------------------------------------------------
__global__ __launch_bounds__(256)
void convert_bf16(const float* __restrict__ x,
                  const float* __restrict__ Wq, const float* __restrict__ Wk,
                  const float* __restrict__ Wv, unsigned short* __restrict__ ws) {
    const int i8 = blockIdx.x*256 + threadIdx.x;
    const float* src; unsigned short* dst; size_t off;
    if (i8 < MSD/8) {
        src = x; dst = ws + XOFF; off = (size_t)i8 * 8;
    } else {
        size_t o = ((size_t)i8 - MSD/8) * 8;
        int wsel = (int)(o / WSZ);
        src = (wsel == 0) ? Wq : (wsel == 1) ? Wk : Wv;
        dst = ws + WOFF + (size_t)wsel*WSZ;
        off = o % WSZ;
    }
    float4 a = *(const float4*)&src[off];
    float4 b = *(const float4*)&src[off+4];
    unsigned short r[8] = { f2bf(a.x), f2bf(a.y), f2bf(a.z), f2bf(a.w),
                            f2bf(b.x), f2bf(b.y), f2bf(b.z), f2bf(b.w) };
    *(bf16x8*)&dst[off] = *(const bf16x8*)r;
}

// ---------------------------------------------------------------------------
// Z-FUSED QKV GEMM, 2 BLOCKS/CU: tile 128m x 64n, grid (8,64) = 512 blocks,
// 512 threads = 8 waves (4m x 2n), wave sub-tile 32x32 per z.
// LDS = A dbuf 32KB + 3 x B dbuf 48KB = 80KB = exactly 160/2 -> 2 co-resident
// blocks per CU: one block computes while the other sits in its barrier
// drain (the 1-block/CU version had zero overlap -> ~48us).
// Per kt per wave: 5 GLD16, 24 MFMA. Epilogue: C via LDS -> coalesced stores.
// ---------------------------------------------------------------------------
__global__ __launch_bounds__(512, 4)
void qkv_fused(const float* __restrict__ bq, const float* __restrict__ bk,
               const float* __restrict__ bv, unsigned short* __restrict__ ws) {
    const unsigned short* Xb = ws + XOFF;
    const unsigned short* Wz0 = ws + WOFF;
    const unsigned short* Wz1 = ws + WOFF + WSZ;
    const unsigned short* Wz2 = ws + WOFF + 2*(size_t)WSZ;

    __shared__ __align__(16) unsigned short As[2][128*64];     // 32KB; front 16KB reused as C-tile
    __shared__ __align__(16) unsigned short Bs[3][2][64*64];   // 48KB

    const int tid  = threadIdx.x;
    const int w    = tid >> 6, l = tid & 63;
    const int quad = l >> 4,  r16 = l & 15;
    const int wm   = w >> 1,  wn  = w & 1;     // 4m x 2n wave grid
    const int n0   = blockIdx.x * 64;
    const int m0   = blockIdx.y * 128;

    const int sr8 = l >> 3, sc = l & 7;

    f32x4 acc[3][2][2];
    #pragma unroll
    for (int z = 0; z < 3; ++z)
        #pragma unroll
        for (int i = 0; i < 2; ++i)
            #pragma unroll
            for (int j = 0; j < 2; ++j) acc[z][i][j] = (f32x4){0.f,0.f,0.f,0.f};

    // stage k-tile (k0) into buffer b:
    //   A: wave w stages rows [w*16, w*16+16)  (2 GLD16)
    //   Bz: wave w stages rows [w*8, w*8+8)    (1 GLD16 each z)
    auto STAGE = [&](int k0, int b) {
        #pragma unroll
        for (int u = 0; u < 2; ++u) {
            const int r0  = w*16 + u*8;
            const int row = r0 + sr8;
            const int c   = sc ^ (row & 7);
            GLD16(&Xb[(size_t)(m0 + row)*DD + k0 + c*8], &As[b][r0*64]);
        }
        const int rb = w*8 + sr8;
        const int cb = sc ^ (rb & 7);
        GLD16(&Wz0[(size_t)(n0 + rb)*DD + k0 + cb*8], &Bs[0][b][(w*8)*64]);
        GLD16(&Wz1[(size_t)(n0 + rb)*DD + k0 + cb*8], &Bs[1][b][(w*8)*64]);
        GLD16(&Wz2[(size_t)(n0 + rb)*DD + k0 + cb*8], &Bs[2][b][(w*8)*64]);
    };

    STAGE(0, 0);    // prologue

    #pragma unroll
    for (int kt = 0; kt < 8; ++kt) {
        __syncthreads();                        // drains DMA(kt)
        if (kt + 1 < 8) STAGE((kt + 1)*64, (kt + 1) & 1);

        const int bb = kt & 1;
        #pragma unroll
        for (int kc = 0; kc < 2; ++kc) {
            bf16x8 a[2];
            #pragma unroll
            for (int i = 0; i < 2; ++i) {
                const int mr = wm*32 + i*16 + r16;
                a[i] = *(const bf16x8*)&As[bb][mr*64 + (((kc*4+quad) ^ (mr&7))*8)];
            }
            bf16x8 b0[2], b1[2], b2[2];
            #pragma unroll
            for (int j = 0; j < 2; ++j) {
                const int nr = wn*32 + j*16 + r16;
                const int sw = ((kc*4+quad) ^ (nr&7))*8;
                b0[j] = *(const bf16x8*)&Bs[0][bb][nr*64 + sw];
                b1[j] = *(const bf16x8*)&Bs[1][bb][nr*64 + sw];
                b2[j] = *(const bf16x8*)&Bs[2][bb][nr*64 + sw];
            }
            __builtin_amdgcn_s_setprio(1);
            #pragma unroll
            for (int i = 0; i < 2; ++i)
                #pragma unroll
                for (int j = 0; j < 2; ++j) {
                    // z<2: operand-swapped -> C^T regs ; z=2: natural -> C regs
                    acc[0][i][j] = __builtin_amdgcn_mfma_f32_16x16x32_bf16(b0[j], a[i], acc[0][i][j], 0, 0, 0);
                    acc[1][i][j] = __builtin_amdgcn_mfma_f32_16x16x32_bf16(b1[j], a[i], acc[1][i][j], 0, 0, 0);
                    acc[2][i][j] = __builtin_amdgcn_mfma_f32_16x16x32_bf16(a[i], b2[j], acc[2][i][j], 0, 0, 0);
                }
            __builtin_amdgcn_s_setprio(0);
        }
    }

    __syncthreads();   // k-loop LDS reads done; reuse As front as C-tile
    unsigned short* Ct = &As[0][0];
    const float qscale = 0.04419417382415922f * 1.4426950408889634f; // 1/sqrt(512)*log2e
    const float* biases[3] = { bq, bk, bv };

    #pragma unroll
    for (int z = 0; z < 3; ++z) {
        unsigned short* dst = ws + (size_t)z*MSD;
        const float* bias = biases[z];

        if (z == 2) {
            // natural C: lane holds C[m = wm*32+i*16+quad*4+reg][n = wn*32+j*16+r16]
            // store TRANSPOSED into Ct[n(64 rows)][m(128)], 16 chunks/row
            #pragma unroll
            for (int j = 0; j < 2; ++j) {
                const int nloc = wn*32 + j*16 + r16;
                const float bz = bias[n0 + nloc];
                #pragma unroll
                for (int i = 0; i < 2; ++i) {
                    const int chunk = wm*4 + i*2 + (quad>>1);   // 0..15
                    const int off   = (quad & 1) * 4;
                    unsigned short r4[4];
                    #pragma unroll
                    for (int reg = 0; reg < 4; ++reg)
                        r4[reg] = f2bf(acc[2][i][j][reg] + bz);
                    *(uint2*)&Ct[nloc*128 + ((chunk ^ (nloc & 7))*8) + off] = *(const uint2*)r4;
                }
            }
        } else {
            // swapped C^T: lane holds C^T[n = wn*32+j*16+quad*4+reg][m = wm*32+i*16+r16]
            // store into Ct[m(128 rows)][n(64)], 8 chunks/row
            #pragma unroll
            for (int j = 0; j < 2; ++j) {
                const int nbase = wn*32 + j*16 + quad*4;
                const float4 bz4 = *(const float4*)&bias[n0 + nbase];
                const int chunk = wn*4 + j*2 + (quad>>1);       // 0..7
                const int off   = (quad & 1) * 4;
                #pragma unroll
                for (int i = 0; i < 2; ++i) {
                    const int mloc = wm*32 + i*16 + r16;
                    float v0 = acc[z][i][j][0] + bz4.x;
                    float v1 = acc[z][i][j][1] + bz4.y;
                    float v2 = acc[z][i][j][2] + bz4.z;
                    float v3 = acc[z][i][j][3] + bz4.w;
                    if (z == 0) { v0 *= qscale; v1 *= qscale; v2 *= qscale; v3 *= qscale; }
                    unsigned short r4[4] = { f2bf(v0), f2bf(v1), f2bf(v2), f2bf(v3) };
                    *(uint2*)&Ct[mloc*64 + ((chunk ^ (mloc & 7))*8) + off] = *(const uint2*)r4;
                }
            }
        }
        __syncthreads();

        // coalesced stores: consecutive lanes -> consecutive 16B chunks
        if (z == 2) {
            const int b_ = m0 >> 12, s0_ = m0 & (SS-1);
            const int h  = n0 >> 6;
            #pragma unroll
            for (int p = 0; p < 2; ++p) {
                const int f = p*512 + tid;
                const int nrow = f >> 4;          // 0..63  (= hd)
                const int mch  = f & 15;          // 0..15
                bf16x8 v = *(const bf16x8*)&Ct[nrow*128 + ((mch ^ (nrow & 7))*8)];
                *(bf16x8*)&dst[((size_t)(b_*HH + h)*HD + nrow)*SS + s0_ + mch*8] = v;
            }
        } else {
            const int hg = n0 >> 6;
            #pragma unroll
            for (int p = 0; p < 2; ++p) {
                const int f = p*512 + tid;
                const int sr = f >> 3;            // 0..127
                const int ch = f & 7;             // 0..7
                bf16x8 v = *(const bf16x8*)&Ct[sr*64 + ((ch ^ (sr & 7))*8)];
                const int mg = m0 + sr;
                const int b_ = mg >> 12, s_ = mg & (SS-1);
                *(bf16x8*)&dst[((size_t)(b_*HH + hg)*SS + s_)*HD + ch*8] = v;
            }
        }
        if (z < 2) __syncthreads();   // C-tile reused by next z
    }
}

// ---------------------------------------------------------------------------
// MFMA flash attention (R10-proven): 4 waves x 32 q (256 threads), balanced
// triple schedule (768 blocks = 3/CU), two-buffer __syncthreads staging,
// in-register P via permlane, hoisted addressing.
// ---------------------------------------------------------------------------
__global__ __launch_bounds__(256, 4)
void attn_mfma(unsigned short* __restrict__ ws, float* __restrict__ out) {
    const int bx = blockIdx.x;           // [0,768)
    const int k_ = bx >> 8;              // triple element 0..2
    const int j_ = bx & 255;
    const int bh = j_ & 15;
    const int ti = j_ >> 4;              // triple 0..15
    const unsigned int e = SCHED[ti*3 + k_];
    const int qb = e & 255;
    const int t0 = (e >> 8) & 255;
    const int t1 = (e >> 16) & 255;
    const int split = !(t0 == 0 && t1 == 2*qb + 2);
    const int half  = (t0 != 0);

    const int tid  = threadIdx.x;
    const int w    = tid >> 6, l = tid & 63;   // w in [0,4)
    const int quad = l >> 4,  r16 = l & 15;
    const int qlo  = qb*128 + w*32;
    const int tdiag = 2*qb + (w >> 1);
    const int qoff  = 32*(w & 1);

    const unsigned short* Qg  = ws;             // pre-scaled by log2e/sqrt(512)
    const unsigned short* Kg  = ws + (size_t)MSD;
    const unsigned short* Vtg = ws + 2*(size_t)MSD;

    __shared__ __align__(16) unsigned short Ks[2][64*64];
    __shared__ __align__(16) unsigned short Vs[2][64*64];

    const size_t kbase = (size_t)bh*SS*HD;
    const size_t vbase = (size_t)bh*HD*SS;

    // Q B-frags: lane holds Q[q = qlo+nt*16+r16][d = kc*32+quad*8+j]
    bf16x8 bqf[2][2];
    #pragma unroll
    for (int nt = 0; nt < 2; ++nt)
        #pragma unroll
        for (int kc = 0; kc < 2; ++kc)
            bqf[nt][kc] = *(const bf16x8*)&Qg[kbase + (size_t)(qlo + nt*16 + r16)*HD + kc*32 + quad*8];

    const f32x4 ZZ = (f32x4){0.f,0.f,0.f,0.f};  // persistent zero C-in
    const unsigned short onep[8] = {0x3F80,0x3F80,0x3F80,0x3F80,0x3F80,0x3F80,0x3F80,0x3F80};
    const bf16x8 ones8 = *(const bf16x8*)onep;  // bf16 1.0 x8

    f32x4 od[4][2];   // O^T accum: [mt -> d][nt -> q]
    #pragma unroll
    for (int mt = 0; mt < 4; ++mt)
        #pragma unroll
        for (int nt = 0; nt < 2; ++nt) od[mt][nt] = ZZ;
    f32x4 lacc[2] = {ZZ, ZZ};   // D[m][q] = sum_k P[k][q], all rows equal

    // ---- hoisted LDS fragment base pointers
    const int x7 = r16 & 7;
    const unsigned short* pK0 = &Ks[0][r16*64 + ((quad     ^ x7)*8)];
    const unsigned short* pK1 = &Ks[0][r16*64 + (((4+quad) ^ x7)*8)];
    const unsigned short* pV0 = &Vs[0][r16*64 + ((quad     ^ x7)*8)];
    const unsigned short* pV1 = &Vs[0][r16*64 + (((4+quad) ^ x7)*8)];

    // ---- hoisted global staging pointers; advance by constant stride/tile
    const int sr8 = l >> 3, sc = l & 7;
    const int row0 = w*16 + sr8,     row1 = w*16 + 8 + sr8;
    const int c0   = sc ^ (row0 & 7), c1  = sc ^ (row1 & 7);
    const unsigned short* kg0 = Kg  + kbase + (size_t)(t0*64 + row0)*HD + c0*8;
    const unsigned short* kg1 = Kg  + kbase + (size_t)(t0*64 + row1)*HD + c1*8;
    const unsigned short* vg0 = Vtg + vbase + (size_t)row0*SS + t0*64 + c0*8;
    const unsigned short* vg1 = Vtg + vbase + (size_t)row1*SS + t0*64 + c1*8;
    unsigned short* lk0 = &Ks[0][(w*16    )*64];
    unsigned short* lk1 = &Ks[0][(w*16 + 8)*64];
    unsigned short* lv0 = &Vs[0][(w*16    )*64];
    unsigned short* lv1 = &Vs[0][(w*16 + 8)*64];

    // prologue: stage tile t0 into buf 0
    GLD16(kg0, lk0); GLD16(kg1, lk1);
    GLD16(vg0, lv0); GLD16(vg1, lv1);
    kg0 += 64*HD; kg1 += 64*HD; vg0 += 64; vg1 += 64;

    for (int t = t0; t < t1; ++t) {
        __syncthreads();                        // drains DMA(t) for all waves

        if (t + 1 < t1) {                       // issue DMA(t+1) into other buf
            const int d1 = ((t + 1 - t0) & 1) * 4096;
            GLD16(kg0, lk0 + d1); GLD16(kg1, lk1 + d1);
            GLD16(vg0, lv0 + d1); GLD16(vg1, lv1 + d1);
            kg0 += 64*HD; kg1 += 64*HD; vg0 += 64; vg1 += 64;
        }

        if (t <= tdiag) {
            const int boff = ((t - t0) & 1) * 4096;

            // ---- S^T = K Q^T : lane holds S^T[key = mt*16+quad*4+reg][q = nt*16+r16]
            f32x4 z[4][2];
            __builtin_amdgcn_s_setprio(1);
            #pragma unroll
            for (int mt = 0; mt < 4; ++mt) {
                bf16x8 ak0 = *(const bf16x8*)(pK0 + boff + mt*1024);
                bf16x8 ak1 = *(const bf16x8*)(pK1 + boff + mt*1024);
                #pragma unroll
                for (int nt = 0; nt < 2; ++nt) {
                    z[mt][nt] = __builtin_amdgcn_mfma_f32_16x16x32_bf16(ak0, bqf[nt][0], ZZ, 0, 0, 0);
                    z[mt][nt] = __builtin_amdgcn_mfma_f32_16x16x32_bf16(ak1, bqf[nt][1], z[mt][nt], 0, 0, 0);
                }
            }
            __builtin_amdgcn_s_setprio(0);

            if (t == tdiag) {   // causal mask on the diagonal tile
                #pragma unroll
                for (int mt = 0; mt < 4; ++mt)
                    #pragma unroll
                    for (int nt = 0; nt < 2; ++nt)
                        #pragma unroll
                        for (int reg = 0; reg < 4; ++reg)
                            if (mt*16 + quad*4 + reg > qoff + nt*16 + r16)
                                z[mt][nt][reg] = -1e30f;
            }

            // ---- P = exp2(z), packed bf16 pairs in-register
            unsigned int X0[4][2], X1[4][2];
            #pragma unroll
            for (int mt = 0; mt < 4; ++mt)
                #pragma unroll
                for (int nt = 0; nt < 2; ++nt) {
                    X0[mt][nt] = pk2bf(__builtin_amdgcn_exp2f(z[mt][nt][0]),
                                       __builtin_amdgcn_exp2f(z[mt][nt][1]));
                    X1[mt][nt] = pk2bf(__builtin_amdgcn_exp2f(z[mt][nt][2]),
                                       __builtin_amdgcn_exp2f(z[mt][nt][3]));
                }

            // ---- cross-quad redistribution: pf[nt][kc] elem j = P[kc*32+quad*8+j][q]
            bf16x8 pf[2][2];
            #pragma unroll
            for (int nt = 0; nt < 2; ++nt)
                #pragma unroll
                for (int kc = 0; kc < 2; ++kc) {
                    unsigned int a0 = X0[2*kc][nt], b0 = X0[2*kc+1][nt];
                    unsigned int a1 = X1[2*kc][nt], b1 = X1[2*kc+1][nt];
                    asm("v_permlane32_swap_b32 %0, %1" : "+v"(a0), "+v"(b0));
                    asm("v_permlane16_swap_b32 %0, %1" : "+v"(a0), "+v"(b0));
                    asm("v_permlane32_swap_b32 %0, %1" : "+v"(a1), "+v"(b1));
                    asm("v_permlane16_swap_b32 %0, %1" : "+v"(a1), "+v"(b1));
                    unsigned int wv[4] = { a0, a1, b0, b1 };   // w0,w1,w2,w3
                    pf[nt][kc] = *(const bf16x8*)wv;
                }

            // ---- O^T += V^T P^T ; l += 1^T P^T (ones-row MFMA)
            __builtin_amdgcn_s_setprio(1);
            #pragma unroll
            for (int nt = 0; nt < 2; ++nt) {
                lacc[nt] = __builtin_amdgcn_mfma_f32_16x16x32_bf16(ones8, pf[nt][0], lacc[nt], 0, 0, 0);
                lacc[nt] = __builtin_amdgcn_mfma_f32_16x16x32_bf16(ones8, pf[nt][1], lacc[nt], 0, 0, 0);
            }
            #pragma unroll
            for (int mt = 0; mt < 4; ++mt) {
                bf16x8 av0 = *(const bf16x8*)(pV0 + boff + mt*1024);
                bf16x8 av1 = *(const bf16x8*)(pV1 + boff + mt*1024);
                #pragma unroll
                for (int nt = 0; nt < 2; ++nt) {
                    od[mt][nt] = __builtin_amdgcn_mfma_f32_16x16x32_bf16(av0, pf[nt][0], od[mt][nt], 0, 0, 0);
                    od[mt][nt] = __builtin_amdgcn_mfma_f32_16x16x32_bf16(av1, pf[nt][1], od[mt][nt], 0, 0, 0);
                }
            }
            __builtin_amdgcn_s_setprio(0);
        }
    }

    if (split) {
        // unnormalized partial store: Opart[p][q=128][d=64] f32, Lpart[p][q]
        const int p = 2*(bh*16 + (qb - 16)) + half;
        float* Op = (float*)(ws + POFF) + (size_t)p*(128*64);
        float* Lp = (float*)(ws + WOFF) + p*128;
        #pragma unroll
        for (int nt = 0; nt < 2; ++nt) {
            const int qloc = w*32 + nt*16 + r16;
            if (quad == 0) Lp[qloc] = lacc[nt][0];
            #pragma unroll
            for (int mt = 0; mt < 4; ++mt)
                *(f32x4*)&Op[(size_t)qloc*64 + mt*16 + quad*4] = od[mt][nt];
        }
    } else {
        const int b_ = bh >> 3, h = bh & 7;
        #pragma unroll
        for (int nt = 0; nt < 2; ++nt) {
            const float inv = 1.0f / lacc[nt][0];
            const int q = qlo + nt*16 + r16;
            float* op = out + ((size_t)(b_*SS + q))*DD + h*HD;
            #pragma unroll
            for (int mt = 0; mt < 4; ++mt) {
                float4 tt;
                tt.x = od[mt][nt][0]*inv; tt.y = od[mt][nt][1]*inv;
                tt.z = od[mt][nt][2]*inv; tt.w = od[mt][nt][3]*inv;
                *(float4*)&op[mt*16 + quad*4] = tt;
            }
        }
    }
}

// ---------------------------------------------------------------------------
// Combine: out = (O_A + O_B) / (l_A + l_B) for the 256 split rows.
// 524288 float4s -> 2048 blocks x 256 threads.
// ---------------------------------------------------------------------------
__global__ __launch_bounds__(256)
void attn_combine(const unsigned short* __restrict__ ws, float* __restrict__ out) {
    const int i  = blockIdx.x*256 + threadIdx.x;   // float4 index
    const int d4 = i & 15;
    const int q  = (i >> 4) & 127;
    const int r  = i >> 11;                        // [0,256): bh*16 + (qb-16)
    const int bh = r >> 4, qb = 16 + (r & 15);

    const float* Opart = (const float*)(ws + POFF);
    const float* Lpart = (const float*)(ws + WOFF);

    const float4 a = *(const float4*)&Opart[((size_t)(2*r)*128 + q)*64 + d4*4];
    const float4 b = *(const float4*)&Opart[((size_t)(2*r + 1)*128 + q)*64 + d4*4];
    const float lt = Lpart[(2*r)*128 + q] + Lpart[(2*r + 1)*128 + q];
    const float inv = 1.0f / lt;

    const int qg = qb*128 + q;
    const int b_ = bh >> 3, h = bh & 7;
    float4 o;
    o.x = (a.x + b.x)*inv; o.y = (a.y + b.y)*inv;
    o.z = (a.z + b.z)*inv; o.w = (a.w + b.w)*inv;
    *(float4*)&out[((size_t)(b_*SS + qg))*DD + h*HD + d4*4] = o;
}

extern "C" void kernel_launch(void* const* d_in, const int* in_sizes, int n_in,
                              void* d_out, int out_size, void* d_ws, size_t ws_size,
                              hipStream_t stream) {
    const float* x  = (const float*)d_in[0];
    const float* Wq = (const float*)d_in[1];
    const float* bq = (const float*)d_in[2];
    const float* Wk = (const float*)d_in[3];
    const float* bk = (const float*)d_in[4];
    const float* Wv = (const float*)d_in[5];
    const float* bv = (const float*)d_in[6];
    float* out = (float*)d_out;
    unsigned short* ws = (unsigned short*)d_ws;

    const int nconv = (MSD/8 + 3*WSZ/8 + 255) / 256;
    convert_bf16<<<nconv, 256, 0, stream>>>(x, Wq, Wk, Wv, ws);

    dim3 ggrid(DD/64, (BB*SS)/128);               // (8, 64) = 512 blocks, 2/CU
    qkv_fused<<<ggrid, 512, 0, stream>>>(bq, bk, bv, ws);

    attn_mfma<<<768, 256, 0, stream>>>(ws, out);
    attn_combine<<<2048, 256, 0, stream>>>(ws, out);
}

// Round 12
// 151.901 us; speedup vs baseline: 1.0164x; 1.0164x over previous
//
#include <hip/hip_runtime.h>
#include <hip/hip_bf16.h>
#include <math.h>

#define BB 2
#define SS 4096
#define DD 512
#define HH 8
#define HD 64
#define MSD (BB*SS*DD)          // 4194304 elements per matrix
#define WSZ (DD*DD)             // 262144 elements per weight

// ws layout (ushort elements):
//   Qb @ 0      [bh][s][hd]  (pre-scaled by log2e/sqrt(512))
//   Kb @ MSD    [bh][s][hd]
//   Vt @ 2*MSD  [bh][hd][s]
//   (4*MSD region unused now -- X is read as f32 directly by qkv)
//   Wb @ 5*MSD  3 x [n][k] bf16   (dead after qkv)
//   Opart @ 3*MSD (as f32): 512 x 128 x 64 f32 = 16.78MB
//   Lpart @ 5*MSD (as f32): 512 x 128 f32, overlays Wb
#define WOFF (5*(size_t)MSD)
#define POFF (3*(size_t)MSD)

typedef __attribute__((ext_vector_type(8))) short bf16x8;
typedef __attribute__((ext_vector_type(4))) float f32x4;

__device__ __forceinline__ unsigned short f2bf(float f) {
    unsigned int u = __float_as_uint(f);
    u += 0x7fff + ((u >> 16) & 1);
    return (unsigned short)(u >> 16);
}
__device__ __forceinline__ unsigned int pk2bf(float a, float b) {
    __hip_bfloat162 h = __float22bfloat162_rn(make_float2(a, b));
    union { __hip_bfloat162 h2; unsigned int u; } cv; cv.h2 = h;
    return cv.u;   // low 16 = a, high 16 = b
}
__device__ __forceinline__ bf16x8 cvt8(const float4& a, const float4& b) {
    unsigned int wv[4] = { pk2bf(a.x, a.y), pk2bf(a.z, a.w),
                           pk2bf(b.x, b.y), pk2bf(b.z, b.w) };
    return *(const bf16x8*)wv;
}

#define GLD16(gsrc, ldst) \
    __builtin_amdgcn_global_load_lds((const __attribute__((address_space(1))) unsigned int*)(gsrc), \
                                     (__attribute__((address_space(3))) unsigned int*)(ldst), 16, 0, 0)

// ---------------------------------------------------------------------------
// Balanced schedule: per bh, 48 chunks packed into 16 triples summing to 66.
// ---------------------------------------------------------------------------
#define CH(qb,t0,t1) ((unsigned)(qb) | ((unsigned)(t0)<<8) | ((unsigned)(t1)<<16))
__device__ __constant__ unsigned int SCHED[48] = {
  CH(31,0,32),  CH(31,32,64), CH(0,0,2),     // 32+32+2
  CH(15,0,32),  CH(29,0,30),  CH(1,0,4),     // 32+30+4
  CH(29,30,60), CH(14,0,30),  CH(2,0,6),     // 30+30+6
  CH(28,0,29),  CH(28,29,58), CH(3,0,8),     // 29+29+8
  CH(27,0,28),  CH(13,0,28),  CH(4,0,10),    // 28+28+10
  CH(26,0,27),  CH(26,27,54), CH(5,0,12),    // 27+27+12
  CH(25,0,26),  CH(12,0,26),  CH(6,0,14),    // 26+26+14
  CH(24,0,25),  CH(24,25,50), CH(7,0,16),    // 25+25+16
  CH(30,0,31),  CH(17,0,18),  CH(16,0,17),   // 31+18+17
  CH(30,31,62), CH(17,18,36), CH(16,17,34),  // 31+18+17
  CH(27,28,56), CH(19,0,20),  CH(8,0,18),    // 28+20+18
  CH(25,26,52), CH(20,0,21),  CH(18,0,19),   // 26+21+19
  CH(23,0,24),  CH(22,0,23),  CH(18,19,38),  // 24+23+19
  CH(23,24,48), CH(21,0,22),  CH(19,20,40),  // 24+22+20
  CH(11,0,24),  CH(21,22,44), CH(9,0,20),    // 24+22+20
  CH(22,23,46), CH(10,0,22),  CH(20,21,42),  // 23+22+21
};

// ---------------------------------------------------------------------------
// fp32 -> bf16 convert, WEIGHTS ONLY (3*WSZ els, 8/thread -> 384 blocks).
// X is no longer converted: qkv reads x f32 directly.
// ---------------------------------------------------------------------------
__global__ __launch_bounds__(256)
void convert_w(const float* __restrict__ Wq, const float* __restrict__ Wk,
               const float* __restrict__ Wv, unsigned short* __restrict__ ws) {
    const int i8 = blockIdx.x*256 + threadIdx.x;
    size_t o = (size_t)i8 * 8;
    const int wsel = (int)(o / WSZ);
    const float* src = (wsel == 0) ? Wq : (wsel == 1) ? Wk : Wv;
    unsigned short* dst = ws + WOFF + (size_t)wsel*WSZ;
    const size_t off = o % WSZ;
    float4 a = *(const float4*)&src[off];
    float4 b = *(const float4*)&src[off+4];
    *(bf16x8*)&dst[off] = cvt8(a, b);
}

// ---------------------------------------------------------------------------
// Z-FUSED QKV GEMM (R7 geometry): tile 128x128, grid (4,64) = 256 blocks =
// 1/CU, 512 threads (8 waves, 2m x 4n). A read DIRECTLY from x (f32):
// reg-staged float4 loads (source pre-swizzled) -> cvt -> ds_write_b128 into
// the same swizzled layout the GLD16 path produced (read side unchanged).
// B staged via global_load_lds from bf16 Wb (R7-proven).
// Per kt: {sync(drain B(kt)); A-write(kt); sync; issue B(kt+1)+A-load(kt+1);
// compute(kt)} -- prefetch hides under compute, second barrier is drain-free.
// ---------------------------------------------------------------------------
__global__ __launch_bounds__(512, 2)
void qkv_fused(const float* __restrict__ x,
               const float* __restrict__ bq, const float* __restrict__ bk,
               const float* __restrict__ bv, unsigned short* __restrict__ ws) {
    const unsigned short* Wz0 = ws + WOFF;
    const unsigned short* Wz1 = ws + WOFF + WSZ;
    const unsigned short* Wz2 = ws + WOFF + 2*(size_t)WSZ;

    __shared__ __align__(16) unsigned short As[2][128*64];      // 32KB; reused as C-tile
    __shared__ __align__(16) unsigned short Bs[3][2][128*64];   // 96KB

    const int tid  = threadIdx.x;
    const int w    = tid >> 6, l = tid & 63;
    const int quad = l >> 4,  r16 = l & 15;
    const int wm   = w >> 2,  wn  = w & 3;     // 2 x 4 wave grid
    const int n0   = blockIdx.x * 128;
    const int m0   = blockIdx.y * 128;

    const int sr8 = l >> 3, sc = l & 7;

    f32x4 acc[3][4][2];
    #pragma unroll
    for (int z = 0; z < 3; ++z)
        #pragma unroll
        for (int i = 0; i < 4; ++i)
            #pragma unroll
            for (int j = 0; j < 2; ++j) acc[z][i][j] = (f32x4){0.f,0.f,0.f,0.f};

    // ---- A staging (f32 -> bf16, reg path), rows w*16+u*8+sr8, u in {0,1}
    const int arow0 = w*16 +     sr8;            // block-local row, u=0
    const int arow1 = w*16 + 8 + sr8;            // u=1
    const float* xa0 = x + (size_t)(m0 + arow0)*DD + (sc ^ (arow0 & 7))*8;
    const float* xa1 = x + (size_t)(m0 + arow1)*DD + (sc ^ (arow1 & 7))*8;
    unsigned short* da0[2] = { &As[0][arow0*64 + sc*8], &As[1][arow0*64 + sc*8] };
    unsigned short* da1[2] = { &As[0][arow1*64 + sc*8], &As[1][arow1*64 + sc*8] };

    // ---- B staging (GLD16 from bf16 Wb), rows w*16+u*8+sr8
    auto STAGE_B = [&](int k0, int b) {
        #pragma unroll
        for (int u = 0; u < 2; ++u) {
            const int r0  = w*16 + u*8;
            const int row = r0 + sr8;
            const int c   = sc ^ (row & 7);
            GLD16(&Wz0[(size_t)(n0 + row)*DD + k0 + c*8], &Bs[0][b][r0*64]);
            GLD16(&Wz1[(size_t)(n0 + row)*DD + k0 + c*8], &Bs[1][b][r0*64]);
            GLD16(&Wz2[(size_t)(n0 + row)*DD + k0 + c*8], &Bs[2][b][r0*64]);
        }
    };

    // prologue: B-DMA(0) -> buf0 ; A-load(0) -> regs
    STAGE_B(0, 0);
    float4 ra[4];
    ra[0] = *(const float4*)xa0; ra[1] = *(const float4*)(xa0+4);
    ra[2] = *(const float4*)xa1; ra[3] = *(const float4*)(xa1+4);
    xa0 += 64; xa1 += 64;

    #pragma unroll
    for (int kt = 0; kt < 8; ++kt) {
        __syncthreads();                        // drains B-DMA(kt); A(kt-1) reads done

        const int bb = kt & 1;
        *(bf16x8*)da0[bb] = cvt8(ra[0], ra[1]); // A-write(kt)
        *(bf16x8*)da1[bb] = cvt8(ra[2], ra[3]);

        __syncthreads();                        // A-writes visible (no vmem in flight)

        if (kt + 1 < 8) {                       // prefetch hides under compute(kt)
            STAGE_B((kt + 1)*64, (kt + 1) & 1);
            ra[0] = *(const float4*)xa0; ra[1] = *(const float4*)(xa0+4);
            ra[2] = *(const float4*)xa1; ra[3] = *(const float4*)(xa1+4);
            xa0 += 64; xa1 += 64;
        }

        #pragma unroll
        for (int kc = 0; kc < 2; ++kc) {
            bf16x8 a[4];
            #pragma unroll
            for (int i = 0; i < 4; ++i) {
                const int mr = wm*64 + i*16 + r16;
                a[i] = *(const bf16x8*)&As[bb][mr*64 + (((kc*4+quad) ^ (mr&7))*8)];
            }
            bf16x8 b0[2], b1[2], b2[2];
            #pragma unroll
            for (int j = 0; j < 2; ++j) {
                const int nr = wn*32 + j*16 + r16;
                const int sw = ((kc*4+quad) ^ (nr&7))*8;
                b0[j] = *(const bf16x8*)&Bs[0][bb][nr*64 + sw];
                b1[j] = *(const bf16x8*)&Bs[1][bb][nr*64 + sw];
                b2[j] = *(const bf16x8*)&Bs[2][bb][nr*64 + sw];
            }
            __builtin_amdgcn_s_setprio(1);
            #pragma unroll
            for (int i = 0; i < 4; ++i)
                #pragma unroll
                for (int j = 0; j < 2; ++j) {
                    // z<2: operand-swapped -> C^T regs ; z=2: natural -> C regs
                    acc[0][i][j] = __builtin_amdgcn_mfma_f32_16x16x32_bf16(b0[j], a[i], acc[0][i][j], 0, 0, 0);
                    acc[1][i][j] = __builtin_amdgcn_mfma_f32_16x16x32_bf16(b1[j], a[i], acc[1][i][j], 0, 0, 0);
                    acc[2][i][j] = __builtin_amdgcn_mfma_f32_16x16x32_bf16(a[i], b2[j], acc[2][i][j], 0, 0, 0);
                }
            __builtin_amdgcn_s_setprio(0);
        }
    }

    __syncthreads();   // k-loop LDS reads done; reuse As as 128x128 C-tile
    unsigned short* Ct = &As[0][0];
    const float qscale = 0.04419417382415922f * 1.4426950408889634f; // 1/sqrt(512)*log2e
    const float* biases[3] = { bq, bk, bv };

    #pragma unroll
    for (int z = 0; z < 3; ++z) {
        unsigned short* dst = ws + (size_t)z*MSD;
        const float* bias = biases[z];

        if (z == 2) {
            #pragma unroll
            for (int j = 0; j < 2; ++j) {
                const int nloc = wn*32 + j*16 + r16;
                const float bz = bias[n0 + nloc];
                #pragma unroll
                for (int i = 0; i < 4; ++i) {
                    const int chunk = wm*8 + i*2 + (quad>>1);
                    const int off   = (quad & 1) * 4;
                    unsigned short r4[4];
                    #pragma unroll
                    for (int reg = 0; reg < 4; ++reg)
                        r4[reg] = f2bf(acc[2][i][j][reg] + bz);
                    *(uint2*)&Ct[nloc*128 + ((chunk ^ (nloc & 7))*8) + off] = *(const uint2*)r4;
                }
            }
        } else {
            #pragma unroll
            for (int j = 0; j < 2; ++j) {
                const int nbase = wn*32 + j*16 + quad*4;
                const float4 bz4 = *(const float4*)&bias[n0 + nbase];
                const int chunk = wn*4 + j*2 + (quad>>1);
                const int off   = (quad & 1) * 4;
                #pragma unroll
                for (int i = 0; i < 4; ++i) {
                    const int mloc = wm*64 + i*16 + r16;
                    float v0 = acc[z][i][j][0] + bz4.x;
                    float v1 = acc[z][i][j][1] + bz4.y;
                    float v2 = acc[z][i][j][2] + bz4.z;
                    float v3 = acc[z][i][j][3] + bz4.w;
                    if (z == 0) { v0 *= qscale; v1 *= qscale; v2 *= qscale; v3 *= qscale; }
                    unsigned short r4[4] = { f2bf(v0), f2bf(v1), f2bf(v2), f2bf(v3) };
                    *(uint2*)&Ct[mloc*128 + ((chunk ^ (mloc & 7))*8) + off] = *(const uint2*)r4;
                }
            }
        }
        __syncthreads();

        if (z == 2) {
            const int b_ = m0 >> 12, s0_ = m0 & (SS-1);
            #pragma unroll
            for (int p = 0; p < 4; ++p) {
                const int f = p*512 + tid;
                const int nrow = f >> 4;          // 0..127
                const int mch  = f & 15;          // 0..15
                bf16x8 v = *(const bf16x8*)&Ct[nrow*128 + ((mch ^ (nrow & 7))*8)];
                const int ng = n0 + nrow;
                const int h = ng >> 6, hd = ng & 63;
                *(bf16x8*)&dst[((size_t)(b_*HH + h)*HD + hd)*SS + s0_ + mch*8] = v;
            }
        } else {
            #pragma unroll
            for (int p = 0; p < 4; ++p) {
                const int f = p*512 + tid;
                const int hh  = f >> 10;          // 0..1
                const int rem = f & 1023;
                const int sr  = rem >> 3;         // 0..127
                const int ch  = rem & 7;
                bf16x8 v = *(const bf16x8*)&Ct[sr*128 + (((hh*8 + ch) ^ (sr & 7))*8)];
                const int mg = m0 + sr;
                const int b_ = mg >> 12, s_ = mg & (SS-1);
                const int hg = (n0 >> 6) + hh;
                *(bf16x8*)&dst[((size_t)(b_*HH + hg)*SS + s_)*HD + ch*8] = v;
            }
        }
        if (z < 2) __syncthreads();   // C-tile reused by next z
    }
}

// ---------------------------------------------------------------------------
// MFMA flash attention (R10-proven): 4 waves x 32 q (256 threads), balanced
// triple schedule (768 blocks = 3/CU), two-buffer __syncthreads staging,
// in-register P via permlane, hoisted addressing.
// ---------------------------------------------------------------------------
__global__ __launch_bounds__(256, 4)
void attn_mfma(unsigned short* __restrict__ ws, float* __restrict__ out) {
    const int bx = blockIdx.x;           // [0,768)
    const int k_ = bx >> 8;              // triple element 0..2
    const int j_ = bx & 255;
    const int bh = j_ & 15;
    const int ti = j_ >> 4;              // triple 0..15
    const unsigned int e = SCHED[ti*3 + k_];
    const int qb = e & 255;
    const int t0 = (e >> 8) & 255;
    const int t1 = (e >> 16) & 255;
    const int split = !(t0 == 0 && t1 == 2*qb + 2);
    const int half  = (t0 != 0);

    const int tid  = threadIdx.x;
    const int w    = tid >> 6, l = tid & 63;   // w in [0,4)
    const int quad = l >> 4,  r16 = l & 15;
    const int qlo  = qb*128 + w*32;
    const int tdiag = 2*qb + (w >> 1);
    const int qoff  = 32*(w & 1);

    const unsigned short* Qg  = ws;             // pre-scaled by log2e/sqrt(512)
    const unsigned short* Kg  = ws + (size_t)MSD;
    const unsigned short* Vtg = ws + 2*(size_t)MSD;

    __shared__ __align__(16) unsigned short Ks[2][64*64];
    __shared__ __align__(16) unsigned short Vs[2][64*64];

    const size_t kbase = (size_t)bh*SS*HD;
    const size_t vbase = (size_t)bh*HD*SS;

    // Q B-frags: lane holds Q[q = qlo+nt*16+r16][d = kc*32+quad*8+j]
    bf16x8 bqf[2][2];
    #pragma unroll
    for (int nt = 0; nt < 2; ++nt)
        #pragma unroll
        for (int kc = 0; kc < 2; ++kc)
            bqf[nt][kc] = *(const bf16x8*)&Qg[kbase + (size_t)(qlo + nt*16 + r16)*HD + kc*32 + quad*8];

    const f32x4 ZZ = (f32x4){0.f,0.f,0.f,0.f};  // persistent zero C-in
    const unsigned short onep[8] = {0x3F80,0x3F80,0x3F80,0x3F80,0x3F80,0x3F80,0x3F80,0x3F80};
    const bf16x8 ones8 = *(const bf16x8*)onep;  // bf16 1.0 x8

    f32x4 od[4][2];   // O^T accum: [mt -> d][nt -> q]
    #pragma unroll
    for (int mt = 0; mt < 4; ++mt)
        #pragma unroll
        for (int nt = 0; nt < 2; ++nt) od[mt][nt] = ZZ;
    f32x4 lacc[2] = {ZZ, ZZ};   // D[m][q] = sum_k P[k][q], all rows equal

    // ---- hoisted LDS fragment base pointers
    const int x7 = r16 & 7;
    const unsigned short* pK0 = &Ks[0][r16*64 + ((quad     ^ x7)*8)];
    const unsigned short* pK1 = &Ks[0][r16*64 + (((4+quad) ^ x7)*8)];
    const unsigned short* pV0 = &Vs[0][r16*64 + ((quad     ^ x7)*8)];
    const unsigned short* pV1 = &Vs[0][r16*64 + (((4+quad) ^ x7)*8)];

    // ---- hoisted global staging pointers; advance by constant stride/tile
    const int sr8 = l >> 3, sc = l & 7;
    const int row0 = w*16 + sr8,     row1 = w*16 + 8 + sr8;
    const int c0   = sc ^ (row0 & 7), c1  = sc ^ (row1 & 7);
    const unsigned short* kg0 = Kg  + kbase + (size_t)(t0*64 + row0)*HD + c0*8;
    const unsigned short* kg1 = Kg  + kbase + (size_t)(t0*64 + row1)*HD + c1*8;
    const unsigned short* vg0 = Vtg + vbase + (size_t)row0*SS + t0*64 + c0*8;
    const unsigned short* vg1 = Vtg + vbase + (size_t)row1*SS + t0*64 + c1*8;
    unsigned short* lk0 = &Ks[0][(w*16    )*64];
    unsigned short* lk1 = &Ks[0][(w*16 + 8)*64];
    unsigned short* lv0 = &Vs[0][(w*16    )*64];
    unsigned short* lv1 = &Vs[0][(w*16 + 8)*64];

    // prologue: stage tile t0 into buf 0
    GLD16(kg0, lk0); GLD16(kg1, lk1);
    GLD16(vg0, lv0); GLD16(vg1, lv1);
    kg0 += 64*HD; kg1 += 64*HD; vg0 += 64; vg1 += 64;

    for (int t = t0; t < t1; ++t) {
        __syncthreads();                        // drains DMA(t) for all waves

        if (t + 1 < t1) {                       // issue DMA(t+1) into other buf
            const int d1 = ((t + 1 - t0) & 1) * 4096;
            GLD16(kg0, lk0 + d1); GLD16(kg1, lk1 + d1);
            GLD16(vg0, lv0 + d1); GLD16(vg1, lv1 + d1);
            kg0 += 64*HD; kg1 += 64*HD; vg0 += 64; vg1 += 64;
        }

        if (t <= tdiag) {
            const int boff = ((t - t0) & 1) * 4096;

            // ---- S^T = K Q^T : lane holds S^T[key = mt*16+quad*4+reg][q = nt*16+r16]
            f32x4 z[4][2];
            __builtin_amdgcn_s_setprio(1);
            #pragma unroll
            for (int mt = 0; mt < 4; ++mt) {
                bf16x8 ak0 = *(const bf16x8*)(pK0 + boff + mt*1024);
                bf16x8 ak1 = *(const bf16x8*)(pK1 + boff + mt*1024);
                #pragma unroll
                for (int nt = 0; nt < 2; ++nt) {
                    z[mt][nt] = __builtin_amdgcn_mfma_f32_16x16x32_bf16(ak0, bqf[nt][0], ZZ, 0, 0, 0);
                    z[mt][nt] = __builtin_amdgcn_mfma_f32_16x16x32_bf16(ak1, bqf[nt][1], z[mt][nt], 0, 0, 0);
                }
            }
            __builtin_amdgcn_s_setprio(0);

            if (t == tdiag) {   // causal mask on the diagonal tile
                #pragma unroll
                for (int mt = 0; mt < 4; ++mt)
                    #pragma unroll
                    for (int nt = 0; nt < 2; ++nt)
                        #pragma unroll
                        for (int reg = 0; reg < 4; ++reg)
                            if (mt*16 + quad*4 + reg > qoff + nt*16 + r16)
                                z[mt][nt][reg] = -1e30f;
            }

            // ---- P = exp2(z), packed bf16 pairs in-register
            unsigned int X0[4][2], X1[4][2];
            #pragma unroll
            for (int mt = 0; mt < 4; ++mt)
                #pragma unroll
                for (int nt = 0; nt < 2; ++nt) {
                    X0[mt][nt] = pk2bf(__builtin_amdgcn_exp2f(z[mt][nt][0]),
                                       __builtin_amdgcn_exp2f(z[mt][nt][1]));
                    X1[mt][nt] = pk2bf(__builtin_amdgcn_exp2f(z[mt][nt][2]),
                                       __builtin_amdgcn_exp2f(z[mt][nt][3]));
                }

            // ---- cross-quad redistribution: pf[nt][kc] elem j = P[kc*32+quad*8+j][q]
            bf16x8 pf[2][2];
            #pragma unroll
            for (int nt = 0; nt < 2; ++nt)
                #pragma unroll
                for (int kc = 0; kc < 2; ++kc) {
                    unsigned int a0 = X0[2*kc][nt], b0 = X0[2*kc+1][nt];
                    unsigned int a1 = X1[2*kc][nt], b1 = X1[2*kc+1][nt];
                    asm("v_permlane32_swap_b32 %0, %1" : "+v"(a0), "+v"(b0));
                    asm("v_permlane16_swap_b32 %0, %1" : "+v"(a0), "+v"(b0));
                    asm("v_permlane32_swap_b32 %0, %1" : "+v"(a1), "+v"(b1));
                    asm("v_permlane16_swap_b32 %0, %1" : "+v"(a1), "+v"(b1));
                    unsigned int wv[4] = { a0, a1, b0, b1 };   // w0,w1,w2,w3
                    pf[nt][kc] = *(const bf16x8*)wv;
                }

            // ---- O^T += V^T P^T ; l += 1^T P^T (ones-row MFMA)
            __builtin_amdgcn_s_setprio(1);
            #pragma unroll
            for (int nt = 0; nt < 2; ++nt) {
                lacc[nt] = __builtin_amdgcn_mfma_f32_16x16x32_bf16(ones8, pf[nt][0], lacc[nt], 0, 0, 0);
                lacc[nt] = __builtin_amdgcn_mfma_f32_16x16x32_bf16(ones8, pf[nt][1], lacc[nt], 0, 0, 0);
            }
            #pragma unroll
            for (int mt = 0; mt < 4; ++mt) {
                bf16x8 av0 = *(const bf16x8*)(pV0 + boff + mt*1024);
                bf16x8 av1 = *(const bf16x8*)(pV1 + boff + mt*1024);
                #pragma unroll
                for (int nt = 0; nt < 2; ++nt) {
                    od[mt][nt] = __builtin_amdgcn_mfma_f32_16x16x32_bf16(av0, pf[nt][0], od[mt][nt], 0, 0, 0);
                    od[mt][nt] = __builtin_amdgcn_mfma_f32_16x16x32_bf16(av1, pf[nt][1], od[mt][nt], 0, 0, 0);
                }
            }
            __builtin_amdgcn_s_setprio(0);
        }
    }

    if (split) {
        // unnormalized partial store: Opart[p][q=128][d=64] f32, Lpart[p][q]
        const int p = 2*(bh*16 + (qb - 16)) + half;
        float* Op = (float*)(ws + POFF) + (size_t)p*(128*64);
        float* Lp = (float*)(ws + WOFF) + p*128;
        #pragma unroll
        for (int nt = 0; nt < 2; ++nt) {
            const int qloc = w*32 + nt*16 + r16;
            if (quad == 0) Lp[qloc] = lacc[nt][0];
            #pragma unroll
            for (int mt = 0; mt < 4; ++mt)
                *(f32x4*)&Op[(size_t)qloc*64 + mt*16 + quad*4] = od[mt][nt];
        }
    } else {
        const int b_ = bh >> 3, h = bh & 7;
        #pragma unroll
        for (int nt = 0; nt < 2; ++nt) {
            const float inv = 1.0f / lacc[nt][0];
            const int q = qlo + nt*16 + r16;
            float* op = out + ((size_t)(b_*SS + q))*DD + h*HD;
            #pragma unroll
            for (int mt = 0; mt < 4; ++mt) {
                float4 tt;
                tt.x = od[mt][nt][0]*inv; tt.y = od[mt][nt][1]*inv;
                tt.z = od[mt][nt][2]*inv; tt.w = od[mt][nt][3]*inv;
                *(float4*)&op[mt*16 + quad*4] = tt;
            }
        }
    }
}

// ---------------------------------------------------------------------------
// Combine: out = (O_A + O_B) / (l_A + l_B) for the 256 split rows.
// 524288 float4s -> 2048 blocks x 256 threads.
// ---------------------------------------------------------------------------
__global__ __launch_bounds__(256)
void attn_combine(const unsigned short* __restrict__ ws, float* __restrict__ out) {
    const int i  = blockIdx.x*256 + threadIdx.x;   // float4 index
    const int d4 = i & 15;
    const int q  = (i >> 4) & 127;
    const int r  = i >> 11;                        // [0,256): bh*16 + (qb-16)
    const int bh = r >> 4, qb = 16 + (r & 15);

    const float* Opart = (const float*)(ws + POFF);
    const float* Lpart = (const float*)(ws + WOFF);

    const float4 a = *(const float4*)&Opart[((size_t)(2*r)*128 + q)*64 + d4*4];
    const float4 b = *(const float4*)&Opart[((size_t)(2*r + 1)*128 + q)*64 + d4*4];
    const float lt = Lpart[(2*r)*128 + q] + Lpart[(2*r + 1)*128 + q];
    const float inv = 1.0f / lt;

    const int qg = qb*128 + q;
    const int b_ = bh >> 3, h = bh & 7;
    float4 o;
    o.x = (a.x + b.x)*inv; o.y = (a.y + b.y)*inv;
    o.z = (a.z + b.z)*inv; o.w = (a.w + b.w)*inv;
    *(float4*)&out[((size_t)(b_*SS + qg))*DD + h*HD + d4*4] = o;
}

extern "C" void kernel_launch(void* const* d_in, const int* in_sizes, int n_in,
                              void* d_out, int out_size, void* d_ws, size_t ws_size,
                              hipStream_t stream) {
    const float* x  = (const float*)d_in[0];
    const float* Wq = (const float*)d_in[1];
    const float* bq = (const float*)d_in[2];
    const float* Wk = (const float*)d_in[3];
    const float* bk = (const float*)d_in[4];
    const float* Wv = (const float*)d_in[5];
    const float* bv = (const float*)d_in[6];
    float* out = (float*)d_out;
    unsigned short* ws = (unsigned short*)d_ws;

    convert_w<<<384, 256, 0, stream>>>(Wq, Wk, Wv, ws);   // 3*WSZ/8/256 = 384

    dim3 ggrid(DD/128, (BB*SS)/128);              // (4, 64) = 256 blocks, 1/CU
    qkv_fused<<<ggrid, 512, 0, stream>>>(x, bq, bk, bv, ws);

    attn_mfma<<<768, 256, 0, stream>>>(ws, out);
    attn_combine<<<2048, 256, 0, stream>>>(ws, out);
}